// Round 11
// baseline (1827.936 us; speedup 1.0000x reference)
//
#include <hip/hip_runtime.h>
#include <stdint.h>

// Problem constants
#define NB 4096
#define NT 200
#define NE 64
// attention: 4E=256 -> 64 -> 32 -> 1 ; final MLP: 272 -> 256 -> 128 -> 1
//
// ABI (proven R2-R10): identity order, fp32 floats, int32 ints, FP32 output.
//
// R11: latency-bound fix (R10: VALUBusy 27%, Occ 23%, HBM 1.7%):
//  - flash-style online softmax: no 51KB keys array; per-wave 16-row chunks
//    staged wave-coherently (no barrier in t-loop). LDS 66.5 -> ~30 KB
//    => 5 blocks/CU instead of 2.
//  - all dot-product chains split into 4 (L1) / 2 (L2) accumulators.
//  - interest accumulated online (keys read once, phase-5 pass deleted).

struct __align__(16) Smem {
    int   hist[NT];            // 800 B
    float q[NE];               // 256
    float w2[NE * 32];         // 8192
    float b2[32];              // 128
    float wo[32];              // 128
    float kchunk[4][16 * NE];  // 16384 (4 KB per wave)
    float ip[4 * NE];          // 1024
    float ml[4][2];            // 32   (m, l per wave)
    float row[272];            // 1088
    float mh1[256];            // 1024
    float mp2[256];            // 1024
    float mh2[128];            // 512
};                              // ~29.9 KB -> 5 blocks/CU (VGPR ~100 -> 5 waves/SIMD)

__global__ __launch_bounds__(256, 4)
void din_fused(const int* __restrict__ target_item,
               const int* __restrict__ history_items,
               const int* __restrict__ history_mask,
               const int* __restrict__ sparse_features,
               const float* __restrict__ dense_features,
               const float* __restrict__ item_table,
               const float* __restrict__ user_table,
               const float* __restrict__ ctx_table,
               const float* __restrict__ att_w1,
               const float* __restrict__ att_b1,
               const float* __restrict__ att_w2,
               const float* __restrict__ att_b2,
               const float* __restrict__ att_wo,
               const float* __restrict__ att_bo,
               const float* __restrict__ mlp_w1,
               const float* __restrict__ mlp_b1,
               const float* __restrict__ mlp_w2,
               const float* __restrict__ mlp_b2,
               const float* __restrict__ out_w,
               const float* __restrict__ out_b,
               float* __restrict__ out)
{
    __shared__ Smem sm;

    const int b   = blockIdx.x;
    const int tid = threadIdx.x;
    const int j   = tid & 63;   // lane
    const int wv  = tid >> 6;   // wave 0..3

    // ---- phase 0: stage per-b / shared small data ----------------------
    if (tid < NT) sm.hist[tid] = history_items[b * NT + tid];
    if (tid < NE) sm.q[tid] = item_table[(size_t)target_item[b] * NE + tid];
    for (int i = tid; i < NE * 32; i += 256) sm.w2[i] = att_w2[i];
    if (tid < 32) { sm.b2[tid] = att_b2[tid]; sm.wo[tid] = att_wo[tid]; }
    const float bo = att_bo[0];
    __syncthreads();

    // ---- W_eff column j + effective bias (registers; 2-acc bias chain) --
    // attn_in = [k, q, k-q, k*q] @ w1 factorizes (q row-constant):
    // h1[j] = relu( sum_e k_e*(w1[e,j]+w1[128+e,j]+q_e*w1[192+e,j])
    //              + b1[j] + sum_e q_e*(w1[64+e,j]-w1[128+e,j]) )
    float weff[NE];
    float bia = att_b1[j], bib = 0.f;
#pragma unroll
    for (int e = 0; e < NE; e += 2) {
        const float qe0 = sm.q[e],     qe1 = sm.q[e + 1];
        const float A0  = att_w1[(size_t)(e)           * NE + j];
        const float B0  = att_w1[(size_t)(64 + e)      * NE + j];
        const float C0  = att_w1[(size_t)(128 + e)     * NE + j];
        const float D0  = att_w1[(size_t)(192 + e)     * NE + j];
        const float A1  = att_w1[(size_t)(e + 1)       * NE + j];
        const float B1  = att_w1[(size_t)(64 + e + 1)  * NE + j];
        const float C1  = att_w1[(size_t)(128 + e + 1) * NE + j];
        const float D1  = att_w1[(size_t)(192 + e + 1) * NE + j];
        weff[e]     = A0 + C0 + qe0 * D0;
        weff[e + 1] = A1 + C1 + qe1 * D1;
        bia += qe0 * (B0 - C0);
        bib += qe1 * (B1 - C1);
    }
    const float bias_eff = bia + bib;

    // ---- fused attention: scores -> online softmax -> interest ----------
    // wave wv handles t = wv + 4*kk, kk = 0..49, in chunks of 16 kk's.
    float m = -INFINITY, l = 0.f, inter = 0.f;  // per-lane interest[j] partial
    float* kch = sm.kchunk[wv];
    const int l4  = j >> 2;     // row-group 0..15 for staging
    const int seg = j & 3;      // 4 lanes per row, 4 float4 each

    for (int c = 0; c < 4; ++c) {
        const int kk0  = 16 * c;
        const int nloc = (kk0 + 16 <= 50) ? 16 : (50 - kk0);

        // stage chunk (wave-coherent LDS region; no block barrier needed)
        const int kkl = kk0 + l4;
        if (kkl < 50) {
            const float4* rowp =
                (const float4*)(item_table + (size_t)sm.hist[wv + 4 * kkl] * NE);
            const float4 a0 = rowp[seg + 0];
            const float4 a1 = rowp[seg + 4];
            const float4 a2 = rowp[seg + 8];
            const float4 a3 = rowp[seg + 12];
            float4* dst = (float4*)(kch + l4 * NE);
            dst[seg + 0]  = a0;
            dst[seg + 4]  = a1;
            dst[seg + 8]  = a2;
            dst[seg + 12] = a3;
        }

        for (int i = 0; i < nloc; ++i) {
            const int t = wv + 4 * (kk0 + i);

            // L1: 64-dot, 4 independent accumulators
            const float4* kv4 = (const float4*)(kch + i * NE);
            float a0 = 0.f, a1 = 0.f, a2 = 0.f, a3 = 0.f;
#pragma unroll
            for (int e4 = 0; e4 < 16; e4 += 4) {
                const float4 k0 = kv4[e4 + 0];
                const float4 k1 = kv4[e4 + 1];
                const float4 k2 = kv4[e4 + 2];
                const float4 k3 = kv4[e4 + 3];
                a0 += k0.x * weff[4 * e4 + 0];  a0 += k0.y * weff[4 * e4 + 1];
                a0 += k0.z * weff[4 * e4 + 2];  a0 += k0.w * weff[4 * e4 + 3];
                a1 += k1.x * weff[4 * e4 + 4];  a1 += k1.y * weff[4 * e4 + 5];
                a1 += k1.z * weff[4 * e4 + 6];  a1 += k1.w * weff[4 * e4 + 7];
                a2 += k2.x * weff[4 * e4 + 8];  a2 += k2.y * weff[4 * e4 + 9];
                a2 += k2.z * weff[4 * e4 + 10]; a2 += k2.w * weff[4 * e4 + 11];
                a3 += k3.x * weff[4 * e4 + 12]; a3 += k3.y * weff[4 * e4 + 13];
                a3 += k3.z * weff[4 * e4 + 14]; a3 += k3.w * weff[4 * e4 + 15];
            }
            const float h1v = fmaxf(((a0 + a1) + (a2 + a3)) + bias_eff, 0.f);

            // L2: 32 outputs, 64-dot split over half-waves, 2 accumulators
            const int o2 = j & 31, half = j >> 5;
            float c0 = 0.f, c1 = 0.f;
#pragma unroll
            for (int kk2 = 0; kk2 < 32; kk2 += 2) {
                const int k = half * 32 + kk2;
                c0 += __shfl(h1v, k, 64)     * sm.w2[k * 32 + o2];
                c1 += __shfl(h1v, k + 1, 64) * sm.w2[(k + 1) * 32 + o2];
            }
            float acc2 = c0 + c1;
            acc2 += __shfl_down(acc2, 32, 64);

            // L3 + full 64-lane butterfly (all lanes end with the score)
            float sc = 0.f;
            if (j < 32) {
                const float h2 = fmaxf(acc2 + sm.b2[o2], 0.f);
                sc = h2 * sm.wo[o2];
            }
            sc += __shfl_xor(sc, 32);
            sc += __shfl_xor(sc, 16);
            sc += __shfl_xor(sc, 8);
            sc += __shfl_xor(sc, 4);
            sc += __shfl_xor(sc, 2);
            sc += __shfl_xor(sc, 1);
            float s = sc + bo;
            s = (history_mask[(size_t)b * NT + t] != 0) ? s : -1e9f;

            // online softmax + interest accumulation (keys read once)
            const float nm = fmaxf(m, s);
            const float cf = __expf(m - nm);   // exp(-inf)=0 on first iter
            const float p  = __expf(s - nm);
            l     = l * cf + p;
            inter = inter * cf + p * kch[i * NE + j];
            m     = nm;
        }
    }

    // ---- merge 4 waves' online-softmax states ---------------------------
    if (j == 0) { sm.ml[wv][0] = m; sm.ml[wv][1] = l; }
    sm.ip[wv * NE + j] = inter;
    __syncthreads();

    // ---- build mlp row [user, ctx, q, interest, dense] ------------------
    if (tid < NE) {
        const float M = fmaxf(fmaxf(sm.ml[0][0], sm.ml[1][0]),
                              fmaxf(sm.ml[2][0], sm.ml[3][0]));
        float L = 0.f, I = 0.f;
#pragma unroll
        for (int w = 0; w < 4; ++w) {
            const float cw = __expf(sm.ml[w][0] - M);
            L += cw * sm.ml[w][1];
            I += cw * sm.ip[w * NE + tid];
        }
        const float inter_final = I / L;
        sm.row[0 + tid]   = user_table[(size_t)sparse_features[b * 2 + 0] * NE + tid];
        sm.row[64 + tid]  = ctx_table[(size_t)sparse_features[b * 2 + 1] * NE + tid];
        sm.row[128 + tid] = sm.q[tid];
        sm.row[192 + tid] = inter_final;
    } else if (tid >= 64 && tid < 80) {
        sm.row[256 + (tid - 64)] = dense_features[(size_t)b * 16 + (tid - 64)];
    }
    __syncthreads();

    // ---- MLP layer 1: 272 -> 256 (4 accumulators) -----------------------
    {
        float a0 = 0.f, a1 = 0.f, a2 = 0.f, a3 = 0.f;
        for (int k = 0; k < 272; k += 4) {
            a0 += sm.row[k + 0] * mlp_w1[(size_t)(k + 0) * 256 + tid];
            a1 += sm.row[k + 1] * mlp_w1[(size_t)(k + 1) * 256 + tid];
            a2 += sm.row[k + 2] * mlp_w1[(size_t)(k + 2) * 256 + tid];
            a3 += sm.row[k + 3] * mlp_w1[(size_t)(k + 3) * 256 + tid];
        }
        sm.mh1[tid] = fmaxf(((a0 + a1) + (a2 + a3)) + mlp_b1[tid], 0.f);
    }
    __syncthreads();

    // ---- MLP layer 2: 256 -> 128 (K split over 2 halves, 2 accs) --------
    {
        const int o = tid & 127, half = tid >> 7;
        float a0 = 0.f, a1 = 0.f;
        for (int kk = 0; kk < 128; kk += 2) {
            const int k = half * 128 + kk;
            a0 += sm.mh1[k]     * mlp_w2[(size_t)k * 128 + o];
            a1 += sm.mh1[k + 1] * mlp_w2[(size_t)(k + 1) * 128 + o];
        }
        sm.mp2[half * 128 + o] = a0 + a1;
    }
    __syncthreads();
    if (tid < 128)
        sm.mh2[tid] = fmaxf(sm.mp2[tid] + sm.mp2[128 + tid] + mlp_b2[tid], 0.f);
    __syncthreads();

    // ---- output: 128 -> 1 (wave 0), FP32 store --------------------------
    if (tid < 64) {
        float a = sm.mh2[tid]      * out_w[tid]
                + sm.mh2[64 + tid] * out_w[64 + tid];
        a += __shfl_xor(a, 32);
        a += __shfl_xor(a, 16);
        a += __shfl_xor(a, 8);
        a += __shfl_xor(a, 4);
        a += __shfl_xor(a, 2);
        a += __shfl_xor(a, 1);
        if (tid == 0) out[b] = a + out_b[0];
    }
}

// ---------------------------------------------------------------------------
extern "C" void kernel_launch(void* const* d_in, const int* in_sizes, int n_in,
                              void* d_out, int out_size, void* d_ws, size_t ws_size,
                              hipStream_t stream)
{
    din_fused<<<NB, 256, 0, stream>>>(
        (const int*)d_in[0],      // target_item
        (const int*)d_in[1],      // history_items
        (const int*)d_in[2],      // history_mask
        (const int*)d_in[3],      // sparse_features
        (const float*)d_in[4],    // dense_features
        (const float*)d_in[5],    // item_table
        (const float*)d_in[6],    // user_table
        (const float*)d_in[7],    // ctx_table
        (const float*)d_in[8],  (const float*)d_in[9],   // att_w1, att_b1
        (const float*)d_in[10], (const float*)d_in[11],  // att_w2, att_b2
        (const float*)d_in[12], (const float*)d_in[13],  // att_wo, att_bo
        (const float*)d_in[14], (const float*)d_in[15],  // mlp_w1, mlp_b1
        (const float*)d_in[16], (const float*)d_in[17],  // mlp_w2, mlp_b2
        (const float*)d_in[18], (const float*)d_in[19],  // out_w, out_b
        (float*)d_out);
}

// Round 12
// 684.383 us; speedup vs baseline: 2.6709x; 2.6709x over previous
//
#include <hip/hip_runtime.h>
#include <stdint.h>

// Problem constants
#define NB 4096
#define NT 200
#define NE 64
// attention: 4E=256 -> 64 -> 32 -> 1 ; final MLP: 272 -> 256 -> 128 -> 1
//
// ABI (proven R2-R10): identity order, fp32 floats, int32 ints, FP32 output.
//
// R12 = R10 memory structure + R11's ILP fix, without the occupancy bomb:
//  - R11 post-mortem: 5 blocks/CU pushed the concurrent random-gather set
//    past the 4 MB per-XCD L2 (3.3 -> 8.2 MB), evicting the MLP weights ->
//    FETCH 97 MB -> 1.36 GB, VALUBusy 12%. L2-residency of weights beats
//    occupancy here. Keep 2 blocks/CU (66.5 KB LDS) deliberately.
//  - R10 was latency-bound (VALU 27%, serial 64-FMA chain per t). Fix:
//    4-acc L1 dots, 2-acc L2 dots, TWO t's in flight per wave iteration,
//    dual-score folded butterfly (lane0 -> t0, lane32 -> t1), 4/2-acc MLP.

struct __align__(16) Smem {
    int    hist[NT];
    float  q[NE];
    float4 keys4[NT * 16];   // 51200 B, block-staged once, reused twice
    float  w2[NE * 32];      // 8192 B
    float  b2[32];
    float  wo[32];
    float  scores[NT];       // scores, then softmax weights
    float  ip[4 * NE];
    float  red_a[4];
    float  red_b[4];
    float  row[272];
    float  mh1[256];
    float  mp2[256];
    float  mh2[128];
};                            // ~66.5 KB -> 2 blocks/CU (intentional)

__global__ __launch_bounds__(256)
void din_fused(const int* __restrict__ target_item,
               const int* __restrict__ history_items,
               const int* __restrict__ history_mask,
               const int* __restrict__ sparse_features,
               const float* __restrict__ dense_features,
               const float* __restrict__ item_table,
               const float* __restrict__ user_table,
               const float* __restrict__ ctx_table,
               const float* __restrict__ att_w1,
               const float* __restrict__ att_b1,
               const float* __restrict__ att_w2,
               const float* __restrict__ att_b2,
               const float* __restrict__ att_wo,
               const float* __restrict__ att_bo,
               const float* __restrict__ mlp_w1,
               const float* __restrict__ mlp_b1,
               const float* __restrict__ mlp_w2,
               const float* __restrict__ mlp_b2,
               const float* __restrict__ out_w,
               const float* __restrict__ out_b,
               float* __restrict__ out)
{
    __shared__ Smem sm;

    const int b   = blockIdx.x;
    const int tid = threadIdx.x;
    const int j   = tid & 63;   // lane
    const int wv  = tid >> 6;   // wave 0..3

    // ---- phase 0: stage small per-b data -------------------------------
    if (tid < NT) sm.hist[tid] = history_items[b * NT + tid];
    if (tid < NE) sm.q[tid] = item_table[(size_t)target_item[b] * NE + tid];
    for (int i = tid; i < NE * 32; i += 256) sm.w2[i] = att_w2[i];
    if (tid < 32) { sm.b2[tid] = att_b2[tid]; sm.wo[tid] = att_wo[tid]; }
    const float bo = att_bo[0];
    __syncthreads();

    // ---- phase 1: gather keys into LDS (coalesced, R10 pattern) --------
    {
        const float4* it4 = (const float4*)item_table;
        for (int i = tid; i < NT * 16; i += 256) {
            const int t = i >> 4, e4 = i & 15;
            sm.keys4[t * 16 + e4] = it4[(size_t)sm.hist[t] * 16 + e4];
        }
    }

    // ---- phase 1b: W_eff column j + effective bias (2-acc bias) --------
    // attn_in = [k, q, k-q, k*q] @ w1 factorizes (q row-constant):
    // h1[j] = relu( sum_e k_e*(w1[e,j]+w1[128+e,j]+q_e*w1[192+e,j])
    //              + b1[j] + sum_e q_e*(w1[64+e,j]-w1[128+e,j]) )
    float weff[NE];
    float bia = att_b1[j], bib = 0.f;
#pragma unroll
    for (int e = 0; e < NE; e += 2) {
        const float qe0 = sm.q[e],     qe1 = sm.q[e + 1];
        const float A0  = att_w1[(size_t)(e)           * NE + j];
        const float B0  = att_w1[(size_t)(64 + e)      * NE + j];
        const float C0  = att_w1[(size_t)(128 + e)     * NE + j];
        const float D0  = att_w1[(size_t)(192 + e)     * NE + j];
        const float A1  = att_w1[(size_t)(e + 1)       * NE + j];
        const float B1  = att_w1[(size_t)(64 + e + 1)  * NE + j];
        const float C1  = att_w1[(size_t)(128 + e + 1) * NE + j];
        const float D1  = att_w1[(size_t)(192 + e + 1) * NE + j];
        weff[e]     = A0 + C0 + qe0 * D0;
        weff[e + 1] = A1 + C1 + qe1 * D1;
        bia += qe0 * (B0 - C0);
        bib += qe1 * (B1 - C1);
    }
    const float bias_eff = bia + bib;
    __syncthreads();

    // ---- phase 3: scores, 2 t's per wave-iteration ----------------------
    const int o2 = j & 31, half = j >> 5;
    for (int tb = 0; tb < NT; tb += 8) {
        const int t0 = tb + wv;         // wave-uniform
        const int t1 = tb + wv + 4;

        // L1: two 64-dots, 4 independent accumulators each (broadcast LDS)
        const float4* kv0 = &sm.keys4[t0 * 16];
        const float4* kv1 = &sm.keys4[t1 * 16];
        float a00 = 0.f, a01 = 0.f, a02 = 0.f, a03 = 0.f;
        float a10 = 0.f, a11 = 0.f, a12 = 0.f, a13 = 0.f;
#pragma unroll
        for (int e4 = 0; e4 < 16; e4 += 4) {
            const float4 p0 = kv0[e4 + 0], p1 = kv0[e4 + 1];
            const float4 p2 = kv0[e4 + 2], p3 = kv0[e4 + 3];
            const float4 q0 = kv1[e4 + 0], q1 = kv1[e4 + 1];
            const float4 q2 = kv1[e4 + 2], q3 = kv1[e4 + 3];
            a00 += p0.x * weff[4*e4+0];  a00 += p0.y * weff[4*e4+1];
            a00 += p0.z * weff[4*e4+2];  a00 += p0.w * weff[4*e4+3];
            a01 += p1.x * weff[4*e4+4];  a01 += p1.y * weff[4*e4+5];
            a01 += p1.z * weff[4*e4+6];  a01 += p1.w * weff[4*e4+7];
            a02 += p2.x * weff[4*e4+8];  a02 += p2.y * weff[4*e4+9];
            a02 += p2.z * weff[4*e4+10]; a02 += p2.w * weff[4*e4+11];
            a03 += p3.x * weff[4*e4+12]; a03 += p3.y * weff[4*e4+13];
            a03 += p3.z * weff[4*e4+14]; a03 += p3.w * weff[4*e4+15];
            a10 += q0.x * weff[4*e4+0];  a10 += q0.y * weff[4*e4+1];
            a10 += q0.z * weff[4*e4+2];  a10 += q0.w * weff[4*e4+3];
            a11 += q1.x * weff[4*e4+4];  a11 += q1.y * weff[4*e4+5];
            a11 += q1.z * weff[4*e4+6];  a11 += q1.w * weff[4*e4+7];
            a12 += q2.x * weff[4*e4+8];  a12 += q2.y * weff[4*e4+9];
            a12 += q2.z * weff[4*e4+10]; a12 += q2.w * weff[4*e4+11];
            a13 += q3.x * weff[4*e4+12]; a13 += q3.y * weff[4*e4+13];
            a13 += q3.z * weff[4*e4+14]; a13 += q3.w * weff[4*e4+15];
        }
        const float h1v0 = fmaxf(((a00 + a01) + (a02 + a03)) + bias_eff, 0.f);
        const float h1v1 = fmaxf(((a10 + a11) + (a12 + a13)) + bias_eff, 0.f);

        // L2: 32 outputs each, split-K over half-waves, 2 accs per t
        float c00 = 0.f, c01 = 0.f, c10 = 0.f, c11 = 0.f;
#pragma unroll
        for (int kk = 0; kk < 32; kk += 2) {
            const int k = half * 32 + kk;
            const float w0 = sm.w2[k * 32 + o2];
            const float w1 = sm.w2[(k + 1) * 32 + o2];
            c00 += __shfl(h1v0, k, 64)     * w0;
            c01 += __shfl(h1v0, k + 1, 64) * w1;
            c10 += __shfl(h1v1, k, 64)     * w0;
            c11 += __shfl(h1v1, k + 1, 64) * w1;
        }
        float acc20 = c00 + c01;  acc20 += __shfl_down(acc20, 32, 64); // lanes 0..31
        float acc21 = c10 + c11;  acc21 += __shfl_up(acc21, 32, 64);   // lanes 32..63

        // L3: lanes 0..31 handle t0, lanes 32..63 handle t1; one folded
        // butterfly (xor 16..1 never crosses the 32-lane boundary).
        const float h2 = fmaxf(((j < 32) ? acc20 : acc21) + sm.b2[o2], 0.f);
        float sc = h2 * sm.wo[o2];
        sc += __shfl_xor(sc, 16);
        sc += __shfl_xor(sc, 8);
        sc += __shfl_xor(sc, 4);
        sc += __shfl_xor(sc, 2);
        sc += __shfl_xor(sc, 1);
        if (j == 0)
            sm.scores[t0] = (history_mask[(size_t)b * NT + t0] != 0) ? (sc + bo) : -1e9f;
        if (j == 32)
            sm.scores[t1] = (history_mask[(size_t)b * NT + t1] != 0) ? (sc + bo) : -1e9f;
    }
    __syncthreads();

    // ---- phase 4: softmax over t ---------------------------------------
    const float v = (tid < NT) ? sm.scores[tid] : -INFINITY;
    float m = v;
#pragma unroll
    for (int s = 32; s; s >>= 1) m = fmaxf(m, __shfl_xor(m, s));
    if (j == 0) sm.red_a[wv] = m;
    __syncthreads();
    const float mx = fmaxf(fmaxf(sm.red_a[0], sm.red_a[1]), fmaxf(sm.red_a[2], sm.red_a[3]));
    const float ex = (tid < NT) ? __expf(v - mx) : 0.f;
    float ssum = ex;
#pragma unroll
    for (int s = 32; s; s >>= 1) ssum += __shfl_xor(ssum, s);
    if (j == 0) sm.red_b[wv] = ssum;
    __syncthreads();
    const float total = sm.red_b[0] + sm.red_b[1] + sm.red_b[2] + sm.red_b[3];
    if (tid < NT) sm.scores[tid] = ex / total;
    __syncthreads();

    // ---- phase 5: interest[e] = sum_t w[t]*keys[t][e] (2 accs) ---------
    {
        const float* kf = (const float*)sm.keys4;
        float p0 = 0.f, p1 = 0.f;
        for (int t = wv; t < NT; t += 8) {
            p0 += sm.scores[t]     * kf[t * NE + j];
            p1 += sm.scores[t + 4] * kf[(t + 4) * NE + j];
        }
        sm.ip[wv * NE + j] = p0 + p1;
    }
    __syncthreads();

    // ---- phase 6: build mlp row [user, ctx, q, interest, dense] --------
    if (tid < NE) {
        const float inter = sm.ip[tid] + sm.ip[64 + tid] + sm.ip[128 + tid] + sm.ip[192 + tid];
        sm.row[0 + tid]   = user_table[(size_t)sparse_features[b * 2 + 0] * NE + tid];
        sm.row[64 + tid]  = ctx_table[(size_t)sparse_features[b * 2 + 1] * NE + tid];
        sm.row[128 + tid] = sm.q[tid];
        sm.row[192 + tid] = inter;
    } else if (tid >= 64 && tid < 80) {
        sm.row[256 + (tid - 64)] = dense_features[(size_t)b * 16 + (tid - 64)];
    }
    __syncthreads();

    // ---- phase 7: MLP layer 1: 272 -> 256 (4 accs) ---------------------
    {
        float a0 = 0.f, a1 = 0.f, a2 = 0.f, a3 = 0.f;
        for (int k = 0; k < 272; k += 4) {
            a0 += sm.row[k + 0] * mlp_w1[(size_t)(k + 0) * 256 + tid];
            a1 += sm.row[k + 1] * mlp_w1[(size_t)(k + 1) * 256 + tid];
            a2 += sm.row[k + 2] * mlp_w1[(size_t)(k + 2) * 256 + tid];
            a3 += sm.row[k + 3] * mlp_w1[(size_t)(k + 3) * 256 + tid];
        }
        sm.mh1[tid] = fmaxf(((a0 + a1) + (a2 + a3)) + mlp_b1[tid], 0.f);
    }
    __syncthreads();

    // ---- phase 8: MLP layer 2: 256 -> 128 (split-K, 2 accs) ------------
    {
        const int o = tid & 127, hf = tid >> 7;
        float a0 = 0.f, a1 = 0.f;
        for (int kk = 0; kk < 128; kk += 2) {
            const int k = hf * 128 + kk;
            a0 += sm.mh1[k]     * mlp_w2[(size_t)k * 128 + o];
            a1 += sm.mh1[k + 1] * mlp_w2[(size_t)(k + 1) * 128 + o];
        }
        sm.mp2[hf * 128 + o] = a0 + a1;
    }
    __syncthreads();
    if (tid < 128)
        sm.mh2[tid] = fmaxf(sm.mp2[tid] + sm.mp2[128 + tid] + mlp_b2[tid], 0.f);
    __syncthreads();

    // ---- phase 9: output: 128 -> 1 (wave 0), FP32 store ----------------
    if (tid < 64) {
        float a = sm.mh2[tid]      * out_w[tid]
                + sm.mh2[64 + tid] * out_w[64 + tid];
        a += __shfl_xor(a, 32);
        a += __shfl_xor(a, 16);
        a += __shfl_xor(a, 8);
        a += __shfl_xor(a, 4);
        a += __shfl_xor(a, 2);
        a += __shfl_xor(a, 1);
        if (tid == 0) out[b] = a + out_b[0];
    }
}

// ---------------------------------------------------------------------------
extern "C" void kernel_launch(void* const* d_in, const int* in_sizes, int n_in,
                              void* d_out, int out_size, void* d_ws, size_t ws_size,
                              hipStream_t stream)
{
    din_fused<<<NB, 256, 0, stream>>>(
        (const int*)d_in[0],      // target_item
        (const int*)d_in[1],      // history_items
        (const int*)d_in[2],      // history_mask
        (const int*)d_in[3],      // sparse_features
        (const float*)d_in[4],    // dense_features
        (const float*)d_in[5],    // item_table
        (const float*)d_in[6],    // user_table
        (const float*)d_in[7],    // ctx_table
        (const float*)d_in[8],  (const float*)d_in[9],   // att_w1, att_b1
        (const float*)d_in[10], (const float*)d_in[11],  // att_w2, att_b2
        (const float*)d_in[12], (const float*)d_in[13],  // att_wo, att_bo
        (const float*)d_in[14], (const float*)d_in[15],  // mlp_w1, mlp_b1
        (const float*)d_in[16], (const float*)d_in[17],  // mlp_w2, mlp_b2
        (const float*)d_in[18], (const float*)d_in[19],  // out_w, out_b
        (float*)d_out);
}

// Round 13
// 481.980 us; speedup vs baseline: 3.7926x; 1.4199x over previous
//
#include <hip/hip_runtime.h>
#include <stdint.h>

#define NB 4096
#define NT 200
#define NE 64
// attention: 4E=256 -> 64 -> 32 -> 1 ; final MLP: 272 -> 256 -> 128 -> 1
//
// ABI (proven R2-R10): identity order, fp32 floats, int32 ints, FP32 output.
//
// R13: transposed attention (lane = t).
//  - R12 post-mortem: VALU floor is ~90us but VALUBusy=32% -- stalls came
//    from per-t bpermutes (DS pipe), the barrier-gated key gather, and the
//    2-block/CU occupancy cap imposed by 51KB keys LDS.
//  - Now: each lane holds its own key row in 64 REGISTERS (loaded first,
//    no barrier before use); W_eff/w2 are LDS broadcast reads; L1+L2 fused
//    per-j into 32 h2 accumulators (zero cross-lane in hot loop); interest
//    via in-register butterfly transpose-reduce (63 shfl once).
//  - LDS 28.4KB, ~140 VGPR -> 3 blocks/CU.
//  - Final MLP split into kernel 2 (16 rows/block): weights amortized 16x,
//    and the attention kernel never touches them (avoids R11's L2 eviction).

// compile-time component access into a float4[16] register array
#define KV(i) (((i)&3)==0 ? kvec[(i)>>2].x : ((i)&3)==1 ? kvec[(i)>>2].y : \
               ((i)&3)==2 ? kvec[(i)>>2].z : kvec[(i)>>2].w)

#define BF_STAGE(S)                                                        \
    {                                                                      \
        const bool hi = (j & (S)) != 0;                                    \
        _Pragma("unroll")                                                  \
        for (int i = 0; i < (S); ++i) {                                    \
            const float snd = hi ? KV(i) : KV(i + (S));                    \
            const float rec = __shfl_xor(snd, (S), 64);                    \
            KV(i) = (hi ? KV(i + (S)) : KV(i)) + rec;                      \
        }                                                                  \
    }

struct __align__(16) SmemA {
    float weffT[64 * 72];   // [j][e], e padded 64->72 (288B rows, 16B-aligned)
    float w2[64 * 32];      // [j][o]
    float q[64];
    float biasj[64];
    float b2[32];
    float wo[32];
    float ip[4 * 64];       // bias partials, later interest partials
    float red_a[4];
    float red_b[4];
};                           // 28448 B -> 3 blocks/CU (VGPR-capped)

__global__ __launch_bounds__(256, 3)
void din_attn(const int* __restrict__ target_item,
              const int* __restrict__ history_items,
              const int* __restrict__ history_mask,
              const int* __restrict__ sparse_features,
              const float* __restrict__ dense_features,
              const float* __restrict__ item_table,
              const float* __restrict__ user_table,
              const float* __restrict__ ctx_table,
              const float* __restrict__ att_w1,
              const float* __restrict__ att_b1,
              const float* __restrict__ att_w2,
              const float* __restrict__ att_b2,
              const float* __restrict__ att_wo,
              const float* __restrict__ att_bo,
              float* __restrict__ mlp_in)   // [NB][272]
{
    __shared__ SmemA sm;

    const int b   = blockIdx.x;
    const int tid = threadIdx.x;
    const int j   = tid & 63;
    const int wv  = tid >> 6;
    const int t   = tid;            // lane = history position
    const bool act = (t < NT);

    // ---- issue own-key loads FIRST (registers; overlaps all staging) ----
    const int hrow = history_items[(size_t)b * NT + (act ? t : NT - 1)];
    float4 kvec[16];
    {
        const float4* rp = (const float4*)(item_table + (size_t)hrow * NE);
#pragma unroll
        for (int i = 0; i < 16; ++i) kvec[i] = rp[i];
    }

    // ---- stage small shared data ----------------------------------------
    if (tid < NE) sm.q[tid] = item_table[(size_t)target_item[b] * NE + tid];
    for (int i = tid; i < NE * 32; i += 256) sm.w2[i] = att_w2[i];
    if (tid < 32) { sm.b2[tid] = att_b2[tid]; sm.wo[tid] = att_wo[tid]; }
    const float bo = att_bo[0];
    __syncthreads();

    // ---- W_eff^T[j][e] + bias partials (thread = (wv, j), 16 e's) -------
    // attn_in = [k, q, k-q, k*q] @ w1 factorizes (q row-constant):
    // h1[j] = relu( sum_e k_e*(w1[e,j]+w1[128+e,j]+q_e*w1[192+e,j])
    //              + b1[j] + sum_e q_e*(w1[64+e,j]-w1[128+e,j]) )
    {
        float pb = 0.f;
        for (int e = wv; e < NE; e += 4) {
            const float qe = sm.q[e];
            const float A  = att_w1[(size_t)(e)       * NE + j];
            const float Bv = att_w1[(size_t)(64 + e)  * NE + j];
            const float C  = att_w1[(size_t)(128 + e) * NE + j];
            const float D  = att_w1[(size_t)(192 + e) * NE + j];
            sm.weffT[j * 72 + e] = A + C + qe * D;
            pb += qe * (Bv - C);
        }
        sm.ip[wv * 64 + j] = pb;
    }
    __syncthreads();
    if (tid < NE)
        sm.biasj[tid] = att_b1[tid] + sm.ip[tid] + sm.ip[64 + tid] +
                        sm.ip[128 + tid] + sm.ip[192 + tid];
    __syncthreads();

    // ---- main loop: h2[o] = sum_j relu(h1_j) * w2[j][o], per lane t -----
    float h2[32];
#pragma unroll
    for (int o = 0; o < 32; ++o) h2[o] = 0.f;

    for (int jj = 0; jj < 64; ++jj) {
        const float4* wrow = (const float4*)(sm.weffT + jj * 72);  // broadcast
        float a0 = 0.f, a1 = 0.f, a2 = 0.f, a3 = 0.f;
#pragma unroll
        for (int g = 0; g < 16; g += 4) {
            const float4 w0 = wrow[g + 0];
            const float4 w1 = wrow[g + 1];
            const float4 w2v = wrow[g + 2];
            const float4 w3 = wrow[g + 3];
            a0 += w0.x * kvec[g + 0].x; a0 += w0.y * kvec[g + 0].y;
            a0 += w0.z * kvec[g + 0].z; a0 += w0.w * kvec[g + 0].w;
            a1 += w1.x * kvec[g + 1].x; a1 += w1.y * kvec[g + 1].y;
            a1 += w1.z * kvec[g + 1].z; a1 += w1.w * kvec[g + 1].w;
            a2 += w2v.x * kvec[g + 2].x; a2 += w2v.y * kvec[g + 2].y;
            a2 += w2v.z * kvec[g + 2].z; a2 += w2v.w * kvec[g + 2].w;
            a3 += w3.x * kvec[g + 3].x; a3 += w3.y * kvec[g + 3].y;
            a3 += w3.z * kvec[g + 3].z; a3 += w3.w * kvec[g + 3].w;
        }
        const float h1 = fmaxf(((a0 + a1) + (a2 + a3)) + sm.biasj[jj], 0.f);

        const float4* w2row = (const float4*)(sm.w2 + jj * 32);    // broadcast
#pragma unroll
        for (int o4 = 0; o4 < 8; ++o4) {
            const float4 ww = w2row[o4];
            h2[4 * o4 + 0] += h1 * ww.x;
            h2[4 * o4 + 1] += h1 * ww.y;
            h2[4 * o4 + 2] += h1 * ww.z;
            h2[4 * o4 + 3] += h1 * ww.w;
        }
    }

    // ---- L3 score per lane ----------------------------------------------
    float s0 = 0.f, s1 = 0.f;
#pragma unroll
    for (int o = 0; o < 32; o += 2) {
        s0 += fmaxf(h2[o]     + sm.b2[o],     0.f) * sm.wo[o];
        s1 += fmaxf(h2[o + 1] + sm.b2[o + 1], 0.f) * sm.wo[o + 1];
    }
    const float scr = s0 + s1 + bo;
    const int mk = act ? history_mask[(size_t)b * NT + t] : 0;
    const float v = act ? ((mk != 0) ? scr : -1e9f) : -INFINITY;

    // ---- softmax over 256 lanes (4-wave reduce) -------------------------
    float m = v;
#pragma unroll
    for (int s = 32; s; s >>= 1) m = fmaxf(m, __shfl_xor(m, s));
    if (j == 0) sm.red_a[wv] = m;
    __syncthreads();
    const float mx = fmaxf(fmaxf(sm.red_a[0], sm.red_a[1]),
                           fmaxf(sm.red_a[2], sm.red_a[3]));
    const float ex = __expf(v - mx);   // -inf -> 0
    float ssum = ex;
#pragma unroll
    for (int s = 32; s; s >>= 1) ssum += __shfl_xor(ssum, s);
    if (j == 0) sm.red_b[wv] = ssum;
    __syncthreads();
    const float total = sm.red_b[0] + sm.red_b[1] + sm.red_b[2] + sm.red_b[3];
    const float w = ex / total;        // softmax weight of this lane's t

    // ---- interest: scale own key row, butterfly transpose-reduce --------
#pragma unroll
    for (int i = 0; i < 64; ++i) KV(i) *= w;
    BF_STAGE(32)
    BF_STAGE(16)
    BF_STAGE(8)
    BF_STAGE(4)
    BF_STAGE(2)
    BF_STAGE(1)
    // lane j now holds this wave's partial interest for e = j
    sm.ip[wv * 64 + j] = kvec[0].x;
    __syncthreads();

    // ---- assemble mlp_in row [user, ctx, q, interest, dense] ------------
    float* row = mlp_in + (size_t)b * 272;
    if (tid < NE) {
        const float inter = sm.ip[tid] + sm.ip[64 + tid] +
                            sm.ip[128 + tid] + sm.ip[192 + tid];
        row[0 + tid]   = user_table[(size_t)sparse_features[b * 2 + 0] * NE + tid];
        row[64 + tid]  = ctx_table[(size_t)sparse_features[b * 2 + 1] * NE + tid];
        row[128 + tid] = sm.q[tid];
        row[192 + tid] = inter;
    } else if (tid >= 64 && tid < 80) {
        row[256 + (tid - 64)] = dense_features[(size_t)b * 16 + (tid - 64)];
    }
}

// ---------------------------------------------------------------------------
// Kernel 2: final MLP 272 -> 256 -> 128 -> 1, 16 rows/block (weights x16 reuse)
// ---------------------------------------------------------------------------
__global__ __launch_bounds__(256)
void din_mlp(const float* __restrict__ mlp_in,
             const float* __restrict__ w1,
             const float* __restrict__ b1,
             const float* __restrict__ w2,
             const float* __restrict__ b2,
             const float* __restrict__ ow,
             const float* __restrict__ ob,
             float* __restrict__ out)
{
    __shared__ float in_lds[16 * 272];
    __shared__ float h1_lds[16 * 256];
    __shared__ float p2_lds[2 * 16 * 128];
    __shared__ float h2_lds[16 * 128];

    const int b0  = blockIdx.x * 16;
    const int tid = threadIdx.x;

    for (int i = tid; i < 16 * 272; i += 256)
        in_lds[i] = mlp_in[(size_t)b0 * 272 + i];
    __syncthreads();

    // layer 1: 272 -> 256 (thread = col, 16 rows in registers)
    {
        float acc[16];
        const float bias = b1[tid];
#pragma unroll
        for (int r = 0; r < 16; ++r) acc[r] = bias;
        for (int k = 0; k < 272; ++k) {
            const float wv = w1[(size_t)k * 256 + tid];
#pragma unroll
            for (int r = 0; r < 16; ++r) acc[r] += in_lds[r * 272 + k] * wv;
        }
#pragma unroll
        for (int r = 0; r < 16; ++r) h1_lds[r * 256 + tid] = fmaxf(acc[r], 0.f);
    }
    __syncthreads();

    // layer 2: 256 -> 128, split-K over two half-blocks
    {
        const int o = tid & 127, half = tid >> 7;
        float acc[16];
#pragma unroll
        for (int r = 0; r < 16; ++r) acc[r] = 0.f;
        for (int kk = 0; kk < 128; ++kk) {
            const int k = half * 128 + kk;
            const float wv = w2[(size_t)k * 128 + o];
#pragma unroll
            for (int r = 0; r < 16; ++r) acc[r] += h1_lds[r * 256 + k] * wv;
        }
#pragma unroll
        for (int r = 0; r < 16; ++r) p2_lds[(half * 16 + r) * 128 + o] = acc[r];
    }
    __syncthreads();
    if (tid < 128) {
        const float bias = b2[tid];
#pragma unroll
        for (int r = 0; r < 16; ++r)
            h2_lds[r * 128 + tid] =
                fmaxf(p2_lds[r * 128 + tid] + p2_lds[(16 + r) * 128 + tid] + bias, 0.f);
    }
    __syncthreads();

    // layer 3: 128 -> 1 (16 lanes per row)
    {
        const int r = tid >> 4, l = tid & 15;
        float a = 0.f;
#pragma unroll
        for (int kk = 0; kk < 8; ++kk) {
            const int k = l * 8 + kk;
            a += h2_lds[r * 128 + k] * ow[k];
        }
        a += __shfl_xor(a, 8, 16);
        a += __shfl_xor(a, 4, 16);
        a += __shfl_xor(a, 2, 16);
        a += __shfl_xor(a, 1, 16);
        if (l == 0) out[b0 + r] = a + ob[0];
    }
}

// ---------------------------------------------------------------------------
extern "C" void kernel_launch(void* const* d_in, const int* in_sizes, int n_in,
                              void* d_out, int out_size, void* d_ws, size_t ws_size,
                              hipStream_t stream)
{
    float* mlp_in = (float*)d_ws;   // 4096*272*4 = 4.46 MB

    din_attn<<<NB, 256, 0, stream>>>(
        (const int*)d_in[0],      // target_item
        (const int*)d_in[1],      // history_items
        (const int*)d_in[2],      // history_mask
        (const int*)d_in[3],      // sparse_features
        (const float*)d_in[4],    // dense_features
        (const float*)d_in[5],    // item_table
        (const float*)d_in[6],    // user_table
        (const float*)d_in[7],    // ctx_table
        (const float*)d_in[8],  (const float*)d_in[9],   // att_w1, att_b1
        (const float*)d_in[10], (const float*)d_in[11],  // att_w2, att_b2
        (const float*)d_in[12], (const float*)d_in[13],  // att_wo, att_bo
        mlp_in);

    din_mlp<<<NB / 16, 256, 0, stream>>>(
        mlp_in,
        (const float*)d_in[14], (const float*)d_in[15],  // mlp_w1, mlp_b1
        (const float*)d_in[16], (const float*)d_in[17],  // mlp_w2, mlp_b2
        (const float*)d_in[18], (const float*)d_in[19],  // out_w, out_b
        (float*)d_out);
}